// Round 6
// baseline (146.384 us; speedup 1.0000x reference)
//
#include <hip/hip_runtime.h>
#include <math.h>

#define D      1024
#define CD     16
#define CS     8192
#define ROWS   16384   // B*L
#define LN_EPS 1e-5f
#define KCHUNK 512            // codes per dist chunk
#define NCHUNK (CS / KCHUNK)  // 16
#define CPAD   56             // padded shorts per code in LDS (48 data + 8 pad)

typedef __attribute__((ext_vector_type(8))) short short8;
typedef __attribute__((ext_vector_type(4))) float f32x4;

__device__ inline unsigned short bf16_rne(float v) {
    unsigned u = __float_as_uint(v);
    unsigned r = u + 0x7FFFu + ((u >> 16) & 1u);
    return (unsigned short)(r >> 16);
}
__device__ inline short8 ld8(const unsigned short* p) { return *(const short8*)p; }

// exact 3-term bf16 split: v = a + b + c, dropped residual ~2^-27 rel
__device__ inline void split3(float v, unsigned short& a, unsigned short& b, unsigned short& c) {
    unsigned u = __float_as_uint(v);
    unsigned r = u + 0x7FFFu + ((u >> 16) & 1u);
    a = (unsigned short)(r >> 16);
    float r1 = v - __uint_as_float(r & 0xFFFF0000u);     // exact
    unsigned u1 = __float_as_uint(r1);
    unsigned r1b = u1 + 0x7FFFu + ((u1 >> 16) & 1u);
    b = (unsigned short)(r1b >> 16);
    float r2 = r1 - __uint_as_float(r1b & 0xFFFF0000u);  // exact
    c = bf16_rne(r2);
}

// -------------------------------------------------------------------------
// pack: blockIdx < 32 -> codebook 3-term split (48 bf16/code) + -0.5||c||^2;
//       blockIdx >= 32 -> W 3-term split in MFMA-B-frag stream order.
// -------------------------------------------------------------------------
__global__ __launch_bounds__(256) void pack_all(const float* __restrict__ W,
                                                const float* __restrict__ cb,
                                                unsigned short* __restrict__ wb,
                                                unsigned short* __restrict__ cbp,
                                                float* __restrict__ nhc)
{
    const int t = threadIdx.x;
    if (blockIdx.x < 32) {
        int k = blockIdx.x * 256 + t;          // 0..8191
        const float* c = cb + (long)k * CD;
        unsigned short* o = cbp + (long)k * 48;
        float csq = 0.f;
        #pragma unroll
        for (int d = 0; d < 16; ++d) {
            float v = c[d];
            csq = fmaf(v, v, csq);
            unsigned short h0, h1, h2;
            split3(v, h0, h1, h2);
            o[d] = h0; o[16 + d] = h1; o[32 + d] = h2;
        }
        nhc[k] = -0.5f * csq;
    } else {
        int tid = (blockIdx.x - 32) * 256 + t; // 0..6143
        int gk   = tid / 192;
        int rem  = tid % 192;
        int term = rem >> 6;
        int L    = rem & 63;
        int n = L & 15, q = L >> 4;
        const float* src = W + n * D + gk * 32 + q * 8;
        unsigned short* dst = wb + (size_t)tid * 8;
        #pragma unroll
        for (int j = 0; j < 8; ++j) {
            unsigned short h0, h1, h2;
            split3(src[j], h0, h1, h2);
            dst[j] = term == 0 ? h0 : (term == 1 ? h1 : h2);
        }
    }
}

// -------------------------------------------------------------------------
// proj_ln: z = LayerNorm(x @ W^T) fused, emitted as 3-term bf16 split.
// Block = 4 waves = 1 row-tile x 4 K-quarters. Grid 1024 -> 4 blocks/CU,
// 16 waves/CU, one resident generation. Two independent MFMA chains/wave.
// -------------------------------------------------------------------------
__global__ __launch_bounds__(256, 4) void proj_ln(const float* __restrict__ x,
                                                  const unsigned short* __restrict__ wb,
                                                  unsigned short* __restrict__ zp)
{
    __shared__ float part[3][64][4];
    const int t = threadIdx.x;
    const int L = t & 63;
    const int kq = t >> 6;
    const int rt = blockIdx.x;
    const int n = L & 15, q = L >> 4;

    const float* xrow = x + (size_t)(rt * 16 + n) * D + kq * 256 + q * 8;
    const unsigned short* wbase = wb + (size_t)(kq * 8) * 1536;

    f32x4 acc0 = {0.f, 0.f, 0.f, 0.f};
    f32x4 acc1 = {0.f, 0.f, 0.f, 0.f};
    #pragma unroll
    for (int kk = 0; kk < 8; ++kk) {
        float4 xa = *(const float4*)(xrow + kk * 32);
        float4 xb = *(const float4*)(xrow + kk * 32 + 4);
        const unsigned short* wp = wbase + (size_t)kk * 1536 + L * 8;
        short8 w0 = ld8(wp);
        short8 w1 = ld8(wp + 512);
        short8 w2 = ld8(wp + 1024);
        float vs[8] = {xa.x, xa.y, xa.z, xa.w, xb.x, xb.y, xb.z, xb.w};
        short8 x0, x1, x2;
        #pragma unroll
        for (int j = 0; j < 8; ++j) {
            unsigned short h0, h1, h2;
            split3(vs[j], h0, h1, h2);
            x0[j] = (short)h0; x1[j] = (short)h1; x2[j] = (short)h2;
        }
        acc0 = __builtin_amdgcn_mfma_f32_16x16x32_bf16(x0, w0, acc0, 0, 0, 0);
        acc1 = __builtin_amdgcn_mfma_f32_16x16x32_bf16(x0, w1, acc1, 0, 0, 0);
        acc0 = __builtin_amdgcn_mfma_f32_16x16x32_bf16(x1, w0, acc0, 0, 0, 0);
        acc1 = __builtin_amdgcn_mfma_f32_16x16x32_bf16(x1, w1, acc1, 0, 0, 0);
        acc0 = __builtin_amdgcn_mfma_f32_16x16x32_bf16(x0, w2, acc0, 0, 0, 0);
        acc1 = __builtin_amdgcn_mfma_f32_16x16x32_bf16(x2, w0, acc1, 0, 0, 0);
    }

    if (kq != 0) {
        #pragma unroll
        for (int r = 0; r < 4; ++r) part[kq - 1][L][r] = acc0[r] + acc1[r];
    }
    __syncthreads();
    if (kq == 0) {
        #pragma unroll
        for (int r = 0; r < 4; ++r) {
            float zv = acc0[r] + acc1[r] + part[0][L][r] + part[1][L][r] + part[2][L][r];
            float s = zv;
            for (int m = 1; m < 16; m <<= 1) s += __shfl_xor(s, m, 64);
            float mu = s * (1.f / 16.f);
            float dd = zv - mu;
            float v2 = dd * dd;
            for (int m = 1; m < 16; m <<= 1) v2 += __shfl_xor(v2, m, 64);
            float var = v2 * (1.f / 16.f);
            float zn = dd / sqrtf(var + LN_EPS);
            unsigned short h0, h1, h2;
            split3(zn, h0, h1, h2);
            unsigned short* zr = zp + (size_t)(rt * 16 + q * 4 + r) * 48;
            zr[n] = h0; zr[16 + n] = h1; zr[32 + n] = h2;
        }
    }
}

// -------------------------------------------------------------------------
// dist_argmin: score = z.c - 0.5||c||^2 (argmin d2 == argmax score).
// 3 MFMAs per 16x16 tile (A-side half-swaps, bias as C of 1st MFMA).
// j=4 row-tiles/wave: 12 MFMAs per 2 ds_read_b128 -> matrix-issue-bound.
// Block = 256 thr (4 waves) covering 16 row-tiles (256 rows); grid 64x16.
// launch_bounds(256,2): VGPR cap 256 (no spill; ~110 live). LDS 58 KB ->
// 2 blocks/CU, 8 waves/CU. Code stride padded to 56 shorts (112 B) to
// spread bank-quads (28 mod 32) across lanes.
// -------------------------------------------------------------------------
__global__ __launch_bounds__(256, 2) void dist_argmin(const unsigned short* __restrict__ zp,
                                                      const unsigned short* __restrict__ cbp,
                                                      const float* __restrict__ nhc,
                                                      float* __restrict__ pbest,
                                                      int* __restrict__ pidx)
{
    __shared__ __align__(16) unsigned short cl[KCHUNK * CPAD];  // 56 KB
    __shared__ float ql[KCHUNK];                                // 2 KB
    const int t = threadIdx.x;
    const int kbase = blockIdx.y * KCHUNK;

    {
        // stage 512 codes x 48 shorts (6 float4 chunks each) into padded layout
        const float4* src = (const float4*)(cbp + (size_t)kbase * 48);
        #pragma unroll
        for (int i = 0; i < 12; ++i) {
            int idx = t + i * 256;         // 0..3071
            int k = idx / 6, c = idx % 6;
            *(float4*)(cl + (size_t)k * CPAD + c * 8) = src[idx];
        }
        if (t < KCHUNK / 4) ((float4*)ql)[t] = ((const float4*)(nhc + kbase))[t];
    }
    __syncthreads();

    const int L = t & 63;
    const int w = t >> 6;
    const int n = L & 15;    // code col (B n) / z row (A m)
    const int q = L >> 4;

    const int oa2 = (q * 8 + 16) & 31;                 // [z1|z0]
    const int oa3 = q < 2 ? 32 + q * 8 : (q - 2) * 8;  // [z2|z0]
    const int ob3 = q < 2 ? q * 8 : 16 + q * 8;        // [c0|c2]

    short8 a1[4], a2[4], a3[4];
    const int rt0 = blockIdx.x * 16 + w * 4;
    #pragma unroll
    for (int j = 0; j < 4; ++j) {
        const unsigned short* zr = zp + (size_t)((rt0 + j) * 16 + n) * 48;
        a1[j] = ld8(zr + q * 8);
        a2[j] = ld8(zr + oa2);
        a3[j] = ld8(zr + oa3);
    }

    float best[4][4];
    int   bi[4][4];
    #pragma unroll
    for (int j = 0; j < 4; ++j)
        #pragma unroll
        for (int r = 0; r < 4; ++r) { best[j][r] = -INFINITY; bi[j][r] = 0; }

    #pragma unroll 2
    for (int tt = 0; tt < KCHUNK / 16; ++tt) {
        const unsigned short* cb_t = cl + (size_t)(tt * 16 + n) * CPAD;
        short8 b1 = ld8(cb_t + q * 8);
        short8 b3 = ld8(cb_t + ob3);
        float bneg = ql[tt * 16 + n];
        f32x4 bias = {bneg, bneg, bneg, bneg};
        int code = kbase + tt * 16 + n;
        f32x4 acc[4];
        #pragma unroll
        for (int j = 0; j < 4; ++j)
            acc[j] = __builtin_amdgcn_mfma_f32_16x16x32_bf16(a1[j], b1, bias, 0, 0, 0);
        #pragma unroll
        for (int j = 0; j < 4; ++j)
            acc[j] = __builtin_amdgcn_mfma_f32_16x16x32_bf16(a2[j], b1, acc[j], 0, 0, 0);
        #pragma unroll
        for (int j = 0; j < 4; ++j)
            acc[j] = __builtin_amdgcn_mfma_f32_16x16x32_bf16(a3[j], b3, acc[j], 0, 0, 0);
        #pragma unroll
        for (int j = 0; j < 4; ++j)
            #pragma unroll
            for (int r = 0; r < 4; ++r)
                if (acc[j][r] > best[j][r]) { best[j][r] = acc[j][r]; bi[j][r] = code; }
    }

    #pragma unroll
    for (int mask = 1; mask < 16; mask <<= 1) {
        #pragma unroll
        for (int j = 0; j < 4; ++j)
            #pragma unroll
            for (int r = 0; r < 4; ++r) {
                float s2 = __shfl_xor(best[j][r], mask, 64);
                int   i2 = __shfl_xor(bi[j][r], mask, 64);
                if (s2 > best[j][r] || (s2 == best[j][r] && i2 < bi[j][r])) {
                    best[j][r] = s2; bi[j][r] = i2;
                }
            }
    }
    if (n == 0) {
        #pragma unroll
        for (int j = 0; j < 4; ++j)
            #pragma unroll
            for (int r = 0; r < 4; ++r) {
                int row = (rt0 + j) * 16 + q * 4 + r;
                pbest[(size_t)row * NCHUNK + blockIdx.y] = best[j][r];
                pidx [(size_t)row * NCHUNK + blockIdx.y] = bi[j][r];
            }
    }
}

// -------------------------------------------------------------------------
// merge: fold 16 partials/row; ascending chunk order + strict '>' keeps the
// earliest winner -> matches np first-min argmin.
// -------------------------------------------------------------------------
__global__ __launch_bounds__(256) void merge_argmin(const float* __restrict__ pbest,
                                                    const int* __restrict__ pidx,
                                                    int* __restrict__ out)
{
    const long row = (long)blockIdx.x * 256 + threadIdx.x;
    float best = -INFINITY;
    int   bi   = 0;
    #pragma unroll
    for (int i = 0; i < NCHUNK; ++i) {
        float s = pbest[row * NCHUNK + i];
        if (s > best) { best = s; bi = pidx[row * NCHUNK + i]; }
    }
    out[row] = bi;
}

// -------------------------------------------------------------------------
extern "C" void kernel_launch(void* const* d_in, const int* in_sizes, int n_in,
                              void* d_out, int out_size, void* d_ws, size_t ws_size,
                              hipStream_t stream)
{
    const float* x  = (const float*)d_in[0];   // 8*2048*1024
    const float* W  = (const float*)d_in[1];   // 16*1024
    const float* cb = (const float*)d_in[2];   // 8192*16
    int* out = (int*)d_out;                    // 16384 int32

    char* ws = (char*)d_ws;
    unsigned short* zp  = (unsigned short*)ws;               // 1.5 MB
    unsigned short* cbp = (unsigned short*)(ws + 0x180000);  // 768 KB
    float* nhc  = (float*)(ws + 0x240000);                   // 32 KB
    unsigned short* wb = (unsigned short*)(ws + 0x248000);   // 96 KB
    float* pbest = (float*)(ws + 0x260000);                  // 1 MB
    int*   pidx  = (int*)  (ws + 0x360000);                  // 1 MB

    pack_all<<<56, 256, 0, stream>>>(W, cb, wb, cbp, nhc);
    proj_ln <<<ROWS / 16, 256, 0, stream>>>(x, wb, zp);
    dist_argmin<<<dim3(ROWS / 256, NCHUNK), 256, 0, stream>>>(zp, cbp, nhc, pbest, pidx);
    merge_argmin<<<ROWS / 256, 256, 0, stream>>>(pbest, pidx, out);
}

// Round 7
// 140.853 us; speedup vs baseline: 1.0393x; 1.0393x over previous
//
#include <hip/hip_runtime.h>
#include <math.h>

#define D      1024
#define CD     16
#define CS     8192
#define ROWS   16384   // B*L
#define LN_EPS 1e-5f
#define KCHUNK 512            // codes per dist chunk
#define NCHUNK (CS / KCHUNK)  // 16

typedef __attribute__((ext_vector_type(8))) short short8;
typedef __attribute__((ext_vector_type(4))) float f32x4;

__device__ inline unsigned short bf16_rne(float v) {
    unsigned u = __float_as_uint(v);
    unsigned r = u + 0x7FFFu + ((u >> 16) & 1u);
    return (unsigned short)(r >> 16);
}
__device__ inline short8 ld8(const unsigned short* p) { return *(const short8*)p; }

// exact 3-term bf16 split: v = a + b + c, dropped residual ~2^-27 rel
__device__ inline void split3(float v, unsigned short& a, unsigned short& b, unsigned short& c) {
    unsigned u = __float_as_uint(v);
    unsigned r = u + 0x7FFFu + ((u >> 16) & 1u);
    a = (unsigned short)(r >> 16);
    float r1 = v - __uint_as_float(r & 0xFFFF0000u);     // exact
    unsigned u1 = __float_as_uint(r1);
    unsigned r1b = u1 + 0x7FFFu + ((u1 >> 16) & 1u);
    b = (unsigned short)(r1b >> 16);
    float r2 = r1 - __uint_as_float(r1b & 0xFFFF0000u);  // exact
    c = bf16_rne(r2);
}

// -------------------------------------------------------------------------
// pack_all:
//  blocks [0,32):    nhc[k] = -0.5*||c_k||^2
//  blocks [32,288):  bstream — codebook as ready-to-load B fragments.
//    granule gid = (T*2+g)*64 + L  (T=tile, g: 0=b1,1=b3, L=lane):
//    b1 = [c0|c1] half (offset q*8 of the 48-short split record),
//    b3 = [c0|c2] half (q<2 ? q*8 : 16+q*8). One thread per granule.
//  blocks [288,312): wb — W split in proj B-frag stream order.
// -------------------------------------------------------------------------
__global__ __launch_bounds__(256) void pack_all(const float* __restrict__ W,
                                                const float* __restrict__ cb,
                                                unsigned short* __restrict__ wb,
                                                unsigned short* __restrict__ bstream,
                                                float* __restrict__ nhc)
{
    const int t = threadIdx.x;
    const int b = blockIdx.x;
    if (b < 32) {
        int k = b * 256 + t;                   // 0..8191
        const float* c = cb + (long)k * CD;
        float csq = 0.f;
        #pragma unroll
        for (int d = 0; d < 16; ++d) csq = fmaf(c[d], c[d], csq);
        nhc[k] = -0.5f * csq;
    } else if (b < 288) {
        int gid = (b - 32) * 256 + t;          // 0..65535
        int L = gid & 63;
        int g = (gid >> 6) & 1;
        int T = gid >> 7;                      // tile 0..511
        int n = L & 15, q = L >> 4;
        int k = T * 16 + n;
        int o = (g == 0) ? q * 8 : (q < 2 ? q * 8 : 16 + q * 8);
        int term = o >> 4;                     // which split term (0/1/2)
        int d0 = o & 15;                       // starting dim
        const float* c = cb + (long)k * CD + d0;
        unsigned short out[8];
        #pragma unroll
        for (int j = 0; j < 8; ++j) {
            unsigned short h0, h1, h2;
            split3(c[j], h0, h1, h2);
            out[j] = term == 0 ? h0 : (term == 1 ? h1 : h2);
        }
        *(short8*)(bstream + (size_t)gid * 8) = *(short8*)out;
    } else {
        int tid = (b - 288) * 256 + t;         // 0..6143
        int gk   = tid / 192;
        int rem  = tid % 192;
        int term = rem >> 6;
        int L    = rem & 63;
        int n = L & 15, q = L >> 4;
        const float* src = W + n * D + gk * 32 + q * 8;
        unsigned short* dst = wb + (size_t)tid * 8;
        #pragma unroll
        for (int j = 0; j < 8; ++j) {
            unsigned short h0, h1, h2;
            split3(src[j], h0, h1, h2);
            dst[j] = term == 0 ? h0 : (term == 1 ? h1 : h2);
        }
    }
}

// -------------------------------------------------------------------------
// proj_ln: z = LayerNorm(x @ W^T) fused, emitted as 3-term bf16 split.
// Block = 4 waves = 1 row-tile x 4 K-quarters. Grid 1024 -> 4 blocks/CU,
// 16 waves/CU. Two independent MFMA chains/wave. (unchanged from r5)
// -------------------------------------------------------------------------
__global__ __launch_bounds__(256, 4) void proj_ln(const float* __restrict__ x,
                                                  const unsigned short* __restrict__ wb,
                                                  unsigned short* __restrict__ zp)
{
    __shared__ float part[3][64][4];
    const int t = threadIdx.x;
    const int L = t & 63;
    const int kq = t >> 6;
    const int rt = blockIdx.x;
    const int n = L & 15, q = L >> 4;

    const float* xrow = x + (size_t)(rt * 16 + n) * D + kq * 256 + q * 8;
    const unsigned short* wbase = wb + (size_t)(kq * 8) * 1536;

    f32x4 acc0 = {0.f, 0.f, 0.f, 0.f};
    f32x4 acc1 = {0.f, 0.f, 0.f, 0.f};
    #pragma unroll
    for (int kk = 0; kk < 8; ++kk) {
        float4 xa = *(const float4*)(xrow + kk * 32);
        float4 xb = *(const float4*)(xrow + kk * 32 + 4);
        const unsigned short* wp = wbase + (size_t)kk * 1536 + L * 8;
        short8 w0 = ld8(wp);
        short8 w1 = ld8(wp + 512);
        short8 w2 = ld8(wp + 1024);
        float vs[8] = {xa.x, xa.y, xa.z, xa.w, xb.x, xb.y, xb.z, xb.w};
        short8 x0, x1, x2;
        #pragma unroll
        for (int j = 0; j < 8; ++j) {
            unsigned short h0, h1, h2;
            split3(vs[j], h0, h1, h2);
            x0[j] = (short)h0; x1[j] = (short)h1; x2[j] = (short)h2;
        }
        acc0 = __builtin_amdgcn_mfma_f32_16x16x32_bf16(x0, w0, acc0, 0, 0, 0);
        acc1 = __builtin_amdgcn_mfma_f32_16x16x32_bf16(x0, w1, acc1, 0, 0, 0);
        acc0 = __builtin_amdgcn_mfma_f32_16x16x32_bf16(x1, w0, acc0, 0, 0, 0);
        acc1 = __builtin_amdgcn_mfma_f32_16x16x32_bf16(x1, w1, acc1, 0, 0, 0);
        acc0 = __builtin_amdgcn_mfma_f32_16x16x32_bf16(x0, w2, acc0, 0, 0, 0);
        acc1 = __builtin_amdgcn_mfma_f32_16x16x32_bf16(x2, w0, acc1, 0, 0, 0);
    }

    if (kq != 0) {
        #pragma unroll
        for (int r = 0; r < 4; ++r) part[kq - 1][L][r] = acc0[r] + acc1[r];
    }
    __syncthreads();
    if (kq == 0) {
        #pragma unroll
        for (int r = 0; r < 4; ++r) {
            float zv = acc0[r] + acc1[r] + part[0][L][r] + part[1][L][r] + part[2][L][r];
            float s = zv;
            for (int m = 1; m < 16; m <<= 1) s += __shfl_xor(s, m, 64);
            float mu = s * (1.f / 16.f);
            float dd = zv - mu;
            float v2 = dd * dd;
            for (int m = 1; m < 16; m <<= 1) v2 += __shfl_xor(v2, m, 64);
            float var = v2 * (1.f / 16.f);
            float zn = dd / sqrtf(var + LN_EPS);
            unsigned short h0, h1, h2;
            split3(zn, h0, h1, h2);
            unsigned short* zr = zp + (size_t)(rt * 16 + q * 4 + r) * 48;
            zr[n] = h0; zr[16 + n] = h1; zr[32 + n] = h2;
        }
    }
}

// -------------------------------------------------------------------------
// dist_argmin: score = z.c - 0.5||c||^2 (argmin d2 == argmax score).
// NO LDS: B-fragments stream straight from L2 (bstream is 1 MB, resident;
// 16B/lane coalesced). 3 MFMAs per tile (A-side half-swaps, bias as C of
// first MFMA), j=4 row-tiles/wave, explicit next-tile prefetch. No barriers,
// no bank conflicts; 4 blocks/CU (VGPR-bound), grid 64x16 = one generation.
// Per-j fused compute+scan keeps live acc regs at 4.
// -------------------------------------------------------------------------
__global__ __launch_bounds__(256, 4) void dist_argmin(const unsigned short* __restrict__ zp,
                                                      const unsigned short* __restrict__ bstream,
                                                      const float* __restrict__ nhc,
                                                      float* __restrict__ pbest,
                                                      int* __restrict__ pidx)
{
    const int t = threadIdx.x;
    const int L = t & 63;
    const int w = t >> 6;
    const int n = L & 15;    // code col (B n) / z row (A m)
    const int q = L >> 4;
    const int kbase = blockIdx.y * KCHUNK;
    const int Tbase = kbase >> 4;            // 16-code tiles

    const short8* bs = (const short8*)bstream + (size_t)Tbase * 128 + L;

    const int oa2 = (q * 8 + 16) & 31;                 // [z1|z0]
    const int oa3 = q < 2 ? 32 + q * 8 : (q - 2) * 8;  // [z2|z0]

    short8 a1[4], a2[4], a3[4];
    const int rt0 = blockIdx.x * 16 + w * 4;
    #pragma unroll
    for (int j = 0; j < 4; ++j) {
        const unsigned short* zr = zp + (size_t)((rt0 + j) * 16 + n) * 48;
        a1[j] = ld8(zr + q * 8);
        a2[j] = ld8(zr + oa2);
        a3[j] = ld8(zr + oa3);
    }

    float best[4][4];
    int   bi[4][4];
    #pragma unroll
    for (int j = 0; j < 4; ++j)
        #pragma unroll
        for (int r = 0; r < 4; ++r) { best[j][r] = -INFINITY; bi[j][r] = 0; }

    // prefetch tile 0
    short8 b1n = bs[0];
    short8 b3n = bs[64];
    float  qn  = nhc[kbase + n];

    for (int tt = 0; tt < KCHUNK / 16; ++tt) {
        short8 b1 = b1n, b3 = b3n;
        float qv = qn;
        if (tt + 1 < KCHUNK / 16) {
            b1n = bs[(tt + 1) * 128];
            b3n = bs[(tt + 1) * 128 + 64];
            qn  = nhc[kbase + (tt + 1) * 16 + n];
        }
        f32x4 bias = {qv, qv, qv, qv};
        int code = kbase + tt * 16 + n;
        #pragma unroll
        for (int j = 0; j < 4; ++j) {
            f32x4 acc;
            acc = __builtin_amdgcn_mfma_f32_16x16x32_bf16(a1[j], b1, bias, 0, 0, 0);
            acc = __builtin_amdgcn_mfma_f32_16x16x32_bf16(a2[j], b1, acc, 0, 0, 0);
            acc = __builtin_amdgcn_mfma_f32_16x16x32_bf16(a3[j], b3, acc, 0, 0, 0);
            #pragma unroll
            for (int r = 0; r < 4; ++r)
                if (acc[r] > best[j][r]) { best[j][r] = acc[r]; bi[j][r] = code; }
        }
    }

    #pragma unroll
    for (int mask = 1; mask < 16; mask <<= 1) {
        #pragma unroll
        for (int j = 0; j < 4; ++j)
            #pragma unroll
            for (int r = 0; r < 4; ++r) {
                float s2 = __shfl_xor(best[j][r], mask, 64);
                int   i2 = __shfl_xor(bi[j][r], mask, 64);
                if (s2 > best[j][r] || (s2 == best[j][r] && i2 < bi[j][r])) {
                    best[j][r] = s2; bi[j][r] = i2;
                }
            }
    }
    if (n == 0) {
        #pragma unroll
        for (int j = 0; j < 4; ++j)
            #pragma unroll
            for (int r = 0; r < 4; ++r) {
                int row = (rt0 + j) * 16 + q * 4 + r;
                pbest[(size_t)row * NCHUNK + blockIdx.y] = best[j][r];
                pidx [(size_t)row * NCHUNK + blockIdx.y] = bi[j][r];
            }
    }
}

// -------------------------------------------------------------------------
// merge: fold 16 partials/row; ascending chunk order + strict '>' keeps the
// earliest winner -> matches np first-min argmin.
// -------------------------------------------------------------------------
__global__ __launch_bounds__(256) void merge_argmin(const float* __restrict__ pbest,
                                                    const int* __restrict__ pidx,
                                                    int* __restrict__ out)
{
    const long row = (long)blockIdx.x * 256 + threadIdx.x;
    float best = -INFINITY;
    int   bi   = 0;
    #pragma unroll
    for (int i = 0; i < NCHUNK; ++i) {
        float s = pbest[row * NCHUNK + i];
        if (s > best) { best = s; bi = pidx[row * NCHUNK + i]; }
    }
    out[row] = bi;
}

// -------------------------------------------------------------------------
extern "C" void kernel_launch(void* const* d_in, const int* in_sizes, int n_in,
                              void* d_out, int out_size, void* d_ws, size_t ws_size,
                              hipStream_t stream)
{
    const float* x  = (const float*)d_in[0];   // 8*2048*1024
    const float* W  = (const float*)d_in[1];   // 16*1024
    const float* cb = (const float*)d_in[2];   // 8192*16
    int* out = (int*)d_out;                    // 16384 int32

    char* ws = (char*)d_ws;
    unsigned short* zp  = (unsigned short*)ws;                  // 1.5 MB
    float* nhc  = (float*)(ws + 0x180000);                      // 32 KB
    unsigned short* wb = (unsigned short*)(ws + 0x188000);      // 96 KB
    unsigned short* bstream = (unsigned short*)(ws + 0x1A0000); // 1 MB
    float* pbest = (float*)(ws + 0x2A0000);                     // 1 MB
    int*   pidx  = (int*)  (ws + 0x3A0000);                     // 1 MB

    pack_all<<<312, 256, 0, stream>>>(W, cb, wb, bstream, nhc);
    proj_ln <<<ROWS / 16, 256, 0, stream>>>(x, wb, zp);
    dist_argmin<<<dim3(ROWS / 256, NCHUNK), 256, 0, stream>>>(zp, bstream, nhc, pbest, pidx);
    merge_argmin<<<ROWS / 256, 256, 0, stream>>>(pbest, pidx, out);
}